// Round 1
// 2882.388 us; speedup vs baseline: 1.3138x; 1.3138x over previous
//
#include <hip/hip_runtime.h>
#include <hip/hip_bf16.h>
#include <math.h>

typedef __hip_bfloat16 bf16;
typedef __attribute__((ext_vector_type(8))) short short8;
typedef __attribute__((ext_vector_type(4))) float floatx4;

#define SEQ   128
#define BATCH 64
#define VOCAB 10000
#define HID   1024
#define TAIL  81920000   // SEQ*BATCH*VOCAB, element offset of h_final in d_out

#define MFMA(a,b,c) __builtin_amdgcn_mfma_f32_16x16x32_bf16((a),(b),(c),0,0,0)

__device__ inline void gl_lds16(const bf16* g, bf16* s) {
  __builtin_amdgcn_global_load_lds(
      (const __attribute__((address_space(1))) void*)g,
      (__attribute__((address_space(3))) void*)s, 16, 0, 0);
}

// read element i of an input tensor that is either fp32 (f=1) or bf16 (f=0)
__device__ inline float ld_in(const void* p, size_t i, int f) {
  return f ? ((const float*)p)[i] : __bfloat162float(((const bf16*)p)[i]);
}

// ---------------------------------------------------------------------------
// Detect input dtype (see prior rounds). flag[0]=1 -> fp32 inputs, 0 -> bf16.
// Also zeroes flag[1], the grid-barrier counter for the persistent kernel.
// ---------------------------------------------------------------------------
__global__ __launch_bounds__(256) void detect(const unsigned short* __restrict__ u,
                                              int* __restrict__ flag) {
  __shared__ int smax;
  if (threadIdx.x == 0) smax = 0;
  __syncthreads();
  int mymax = 0;
  for (int i = threadIdx.x * 2; i < 4096; i += 512) {   // even indices only
    int e = (u[i] >> 7) & 0xFF;
    mymax = max(mymax, e);
  }
  atomicMax(&smax, mymax);
  __syncthreads();
  if (threadIdx.x == 0) {
    flag[0] = (smax >= 0xF0) ? 1 : 0;
    flag[1] = 0;                                        // grid barrier counter
  }
}

// ---------------------------------------------------------------------------
__global__ __launch_bounds__(256) void convert_any(const void* __restrict__ src,
                                                   bf16* __restrict__ dst, int n,
                                                   const int* __restrict__ flagp) {
  int f = *flagp;
  for (int i = blockIdx.x * 256 + threadIdx.x; i < n; i += gridDim.x * 256)
    dst[i] = __float2bfloat16(ld_in(src, (size_t)i, f));
}

// ---------------------------------------------------------------------------
// Transpose the 4 recurrence weight matrices into bf16 [n][k] (K-contiguous).
// Wt layout: z=0 Wx0^T, z=1 Wh0^T, z=2 Wx1^T, z=3 Wh1^T (each 1024x1024).
// ---------------------------------------------------------------------------
__global__ __launch_bounds__(256) void transpose4(const void* __restrict__ Wx,
                                                  const void* __restrict__ Wh,
                                                  bf16* __restrict__ Wt,
                                                  const int* __restrict__ flagp) {
  __shared__ bf16 tile[64][65];
  int f = *flagp;
  int z = blockIdx.z;
  const void* src = (z & 1) ? Wh : Wx;
  size_t loff = (z >> 1) ? (size_t)HID * HID : 0;
  bf16* dst = Wt + (size_t)z * HID * HID;
  int r0 = blockIdx.x * 64, c0 = blockIdx.y * 64;
  int t = threadIdx.x, cc = t & 63, rg = t >> 6;
  #pragma unroll
  for (int i = 0; i < 16; ++i) {
    int r = rg * 16 + i;
    tile[r][cc] = __float2bfloat16(ld_in(src, loff + (size_t)(r0 + r) * HID + c0 + cc, f));
  }
  __syncthreads();
  #pragma unroll
  for (int i = 0; i < 16; ++i) {
    int j = rg * 16 + i;
    dst[(size_t)(c0 + j) * HID + r0 + cc] = tile[cc][j];  // dst[j][k]=src[k][j]
  }
}

// ---------------------------------------------------------------------------
// A0 = emb[tok] @ Wx0 + b0   (fp32 out, [8192][1024]).  m97-style 128x128x32.
// ---------------------------------------------------------------------------
__global__ __launch_bounds__(256) void gemm_a0(
    const int*  __restrict__ tok,    // [8192]
    const bf16* __restrict__ emb,    // [VOCAB][HID] bf16
    const bf16* __restrict__ Wx0t,   // [HID][HID]  (n,k)
    const bf16* __restrict__ b0,     // [HID] bf16
    float* __restrict__ A0)          // [8192][HID]
{
  __shared__ __align__(16) bf16 sA[128 * 32];
  __shared__ __align__(16) bf16 sB[128 * 32];
  int m0 = blockIdx.x * 128, n0 = blockIdx.y * 128;
  int t = threadIdx.x, lane = t & 63, w = t >> 6;
  int wm = (w >> 1) * 64, wn = (w & 1) * 64;
  int quad = lane >> 4, l16 = lane & 15;

  int r0 = t >> 2, kc = t & 3;
  const bf16* ga0 = emb + (size_t)tok[m0 + r0] * HID + kc * 8;
  const bf16* ga1 = emb + (size_t)tok[m0 + r0 + 64] * HID + kc * 8;
  const bf16* gb0 = Wx0t + (size_t)(n0 + r0) * HID + kc * 8;
  const bf16* gb1 = gb0 + (size_t)64 * HID;
  bf16* sa0 = sA + t * 8;  bf16* sa1 = sA + (t + 256) * 8;
  bf16* sb0 = sB + t * 8;  bf16* sb1 = sB + (t + 256) * 8;

  floatx4 acc[4][4];
  #pragma unroll
  for (int j = 0; j < 4; ++j) {
    float bv = __bfloat162float(b0[n0 + wn + j * 16 + l16]);
    #pragma unroll
    for (int i = 0; i < 4; ++i) acc[i][j] = (floatx4){bv, bv, bv, bv};
  }

  for (int kt = 0; kt < 32; ++kt) {
    gl_lds16(ga0, sa0); gl_lds16(ga1, sa1);
    gl_lds16(gb0, sb0); gl_lds16(gb1, sb1);
    ga0 += 32; ga1 += 32; gb0 += 32; gb1 += 32;
    __syncthreads();
    short8 af[4], bfr[4];
    #pragma unroll
    for (int i = 0; i < 4; ++i)
      af[i] = *(const short8*)(sA + (wm + i * 16 + l16) * 32 + quad * 8);
    #pragma unroll
    for (int j = 0; j < 4; ++j)
      bfr[j] = *(const short8*)(sB + (wn + j * 16 + l16) * 32 + quad * 8);
    #pragma unroll
    for (int i = 0; i < 4; ++i)
      #pragma unroll
      for (int j = 0; j < 4; ++j)
        acc[i][j] = MFMA(af[i], bfr[j], acc[i][j]);
    __syncthreads();
  }

  #pragma unroll
  for (int i = 0; i < 4; ++i)
    #pragma unroll
    for (int j = 0; j < 4; ++j)
      #pragma unroll
      for (int r = 0; r < 4; ++r) {
        int row = wm + i * 16 + quad * 4 + r;
        int col = wn + j * 16 + l16;
        A0[(size_t)(m0 + row) * HID + n0 + col] = acc[i][j][r];
      }
}

// ---------------------------------------------------------------------------
// Device-scope grid barrier: monotonic counter, no reset race.
// Writer side: __threadfence() + release-add flush dirty L2 lines to LLC.
// Reader side: acquire-load + __threadfence() invalidate L1/L2 before reads.
// Safe because all 96 blocks are co-resident (96 < 256 CUs, 64KB LDS/block).
// ---------------------------------------------------------------------------
__device__ inline void gridbar(int* cnt, int expect) {
  __syncthreads();
  if (threadIdx.x == 0) {
    __threadfence();
    __hip_atomic_fetch_add(cnt, 1, __ATOMIC_RELEASE, __HIP_MEMORY_SCOPE_AGENT);
    while (__hip_atomic_load(cnt, __ATOMIC_ACQUIRE, __HIP_MEMORY_SCOPE_AGENT) < expect)
      __builtin_amdgcn_s_sleep(1);
    __threadfence();
  }
  __syncthreads();
}

// ---------------------------------------------------------------------------
// Persistent wavefront: ALL 129 recurrence steps in one kernel.
//   blocks  0..31 (h0, N=32): h0[k]   = tanh(A0[k] + h0[k-1] @ Wh0)
//   blocks 32..95 (h1, N=16): h1[k-1] = tanh(h0[k-1]@Wx1 + h1[k-2]@Wh1 + b1)
// Weight slices live in LDS for the whole kernel, stored as [kt][j][quad][l16]
// 16B chunks so every hot-loop B-read is sW + lane*16 (+ const) -> each wave
// reads 1024 contiguous bytes: zero bank conflicts, zero swizzle math.
// ---------------------------------------------------------------------------
__global__ __launch_bounds__(256) void wavefront_persist(
    const float* __restrict__ A0,
    const bf16* __restrict__ Wt,      // 4x[1024][1024]: Wx0t,Wh0t,Wx1t,Wh1t
    const bf16* __restrict__ bvecB,   // [2*HID] bf16
    const bf16* __restrict__ hidB,    // [2][64][HID] bf16
    bf16* __restrict__ h0a, bf16* __restrict__ h0b,
    bf16* __restrict__ h1a, bf16* __restrict__ h1b,
    bf16* __restrict__ H1hist,        // [8192][HID]
    void* __restrict__ outv,
    int* __restrict__ flagp)          // flagp[0]=dtype flag, flagp[1]=barrier
{
  __shared__ short8 sW8[4096];        // 64 KB
  char* sWb = (char*)sW8;
  const int f = flagp[0];
  int* bar = flagp + 1;
  const int blk = blockIdx.x;
  const int t = threadIdx.x, lane = t & 63, w = t >> 6;
  const int quad = lane >> 4, l16 = lane & 15;
  const int m = w * 16;               // wave w: rows m..m+15
  const bool isH1 = blk >= 32;

  const bf16* Wh0t = Wt + (size_t)1 * HID * HID;
  const bf16* Wx1t = Wt + (size_t)2 * HID * HID;
  const bf16* Wh1t = Wt + (size_t)3 * HID * HID;

  // ---- one-time LDS staging of this block's weight slice(s) ----
  // chunk (row, c16) -> LDS offset (c16>>2)*R*64 + (row>>4)*1024 + (c16&3)*256 + (row&15)*16
  if (!isH1) {
    const int n0 = blk * 32;          // R = 32 rows of Wh0^T
    #pragma unroll
    for (int i = 0; i < 16; ++i) {
      int idx = i * 256 + t;          // 0..4095 ; coalesced global reads
      int row = idx >> 7, c16 = idx & 127;
      short8 v = *(const short8*)(Wh0t + (size_t)(n0 + row) * HID + c16 * 8);
      int off = (c16 >> 2) * 2048 + (row >> 4) * 1024 + (c16 & 3) * 256 + (row & 15) * 16;
      *(short8*)(sWb + off) = v;
    }
  } else {
    const int n0 = (blk - 32) * 16;   // R = 16 rows each of Wx1^T, Wh1^T
    #pragma unroll
    for (int i = 0; i < 8; ++i) {
      int idx = i * 256 + t;          // 0..2047
      int row = idx >> 7, c16 = idx & 127;
      int off = (c16 >> 2) * 1024 + (c16 & 3) * 256 + (row & 15) * 16;
      *(short8*)(sWb + off)         = *(const short8*)(Wx1t + (size_t)(n0 + row) * HID + c16 * 8);
      *(short8*)(sWb + 32768 + off) = *(const short8*)(Wh1t + (size_t)(n0 + row) * HID + c16 * 8);
    }
  }
  __syncthreads();

  for (int k = 0; k <= 128; ++k) {
    if (!isH1) {
      if (k <= 127) {
        const int n0 = blk * 32;
        const bf16* hp = (k == 0) ? hidB : ((k & 1) ? h0a : h0b);    // h0[k-1]
        const bf16* aB = hp + (size_t)(m + l16) * HID + quad * 8;
        const char* b0p = sWb + lane * 16;          // j=0 cols, kt stride 2048
        const char* b1p = sWb + 1024 + lane * 16;   // j=1 cols
        floatx4 acc[2] = {};
        #pragma unroll 8
        for (int kt = 0; kt < 32; ++kt) {
          short8 a = *(const short8*)(aB + kt * 32);
          acc[0] = MFMA(a, *(const short8*)(b0p + kt * 2048), acc[0]);
          acc[1] = MFMA(a, *(const short8*)(b1p + kt * 2048), acc[1]);
        }
        bf16* hw = (k & 1) ? h0b : h0a;                              // h0[k]
        #pragma unroll
        for (int j = 0; j < 2; ++j)
          #pragma unroll
          for (int r = 0; r < 4; ++r) {
            int row = m + quad * 4 + r, col = n0 + j * 16 + l16;
            float pre = acc[j][r] + A0[(size_t)(k * 64 + row) * HID + col];
            float v = tanhf(pre);
            bf16 bv = __float2bfloat16(v);
            hw[row * HID + col] = bv;
            if (k == 127) {                                          // h_final[0]
              size_t o = (size_t)TAIL + row * HID + col;
              if (f) ((float*)outv)[o] = v; else ((bf16*)outv)[o] = bv;
            }
          }
      }
    } else {
      if (k >= 1) {
        const int n0 = (blk - 32) * 16;
        const bf16* a1p = (k & 1) ? h0a : h0b;                       // h0[k-1]
        const bf16* a2p = (k == 1) ? (hidB + 64 * HID)
                                   : ((k & 1) ? h1a : h1b);          // h1[k-2]
        const bf16* aB1 = a1p + (size_t)(m + l16) * HID + quad * 8;
        const bf16* aB2 = a2p + (size_t)(m + l16) * HID + quad * 8;
        const char* bXp = sWb + lane * 16;           // Wx1 slice, kt stride 1024
        const char* bHp = sWb + 32768 + lane * 16;   // Wh1 slice
        floatx4 accX = {}, accH = {};
        #pragma unroll 8
        for (int kt = 0; kt < 32; ++kt) {
          short8 a = *(const short8*)(aB1 + kt * 32);
          accX = MFMA(a, *(const short8*)(bXp + kt * 1024), accX);
          short8 c = *(const short8*)(aB2 + kt * 32);
          accH = MFMA(c, *(const short8*)(bHp + kt * 1024), accH);
        }
        bf16* hw = (k & 1) ? h1b : h1a;                              // h1[k-1]
        #pragma unroll
        for (int r = 0; r < 4; ++r) {
          int row = m + quad * 4 + r, col = n0 + l16;
          float v = tanhf(accX[r] + accH[r] + __bfloat162float(bvecB[HID + col]));
          bf16 bv = __float2bfloat16(v);
          hw[row * HID + col] = bv;
          H1hist[(size_t)((k - 1) * 64 + row) * HID + col] = bv;
          if (k == 128) {                                            // h_final[1]
            size_t o = (size_t)TAIL + 64 * HID + row * HID + col;
            if (f) ((float*)outv)[o] = v; else ((bf16*)outv)[o] = bv;
          }
        }
      }
    }
    if (k < 128) gridbar(bar, (k + 1) * 96);
  }
}

// ---------------------------------------------------------------------------
// logits = H1 @ fcW^T + fcb  -> [8192][10000]. fcW already [V][K].
// ---------------------------------------------------------------------------
__global__ __launch_bounds__(256) void gemm_logits(
    const bf16* __restrict__ H1,    // [8192][HID]
    const bf16* __restrict__ fcW,   // [VOCAB][HID] bf16
    const bf16* __restrict__ fcb,   // [VOCAB] bf16
    void* __restrict__ outv,        // [8192][VOCAB] fp32 or bf16
    const int* __restrict__ flagp)
{
  __shared__ __align__(16) bf16 sA[128 * 32];
  __shared__ __align__(16) bf16 sB[128 * 32];
  int f = *flagp;
  int m0 = blockIdx.x * 128, n0 = blockIdx.y * 128;
  int t = threadIdx.x, lane = t & 63, w = t >> 6;
  int wm = (w >> 1) * 64, wn = (w & 1) * 64;
  int quad = lane >> 4, l16 = lane & 15;

  int r0 = t >> 2, kc = t & 3;
  int rB0 = n0 + r0;      if (rB0 > VOCAB - 1) rB0 = VOCAB - 1;
  int rB1 = n0 + r0 + 64; if (rB1 > VOCAB - 1) rB1 = VOCAB - 1;
  const bf16* ga0 = H1 + (size_t)(m0 + r0) * HID + kc * 8;
  const bf16* ga1 = ga0 + (size_t)64 * HID;
  const bf16* gb0 = fcW + (size_t)rB0 * HID + kc * 8;
  const bf16* gb1 = fcW + (size_t)rB1 * HID + kc * 8;
  bf16* sa0 = sA + t * 8;  bf16* sa1 = sA + (t + 256) * 8;
  bf16* sb0 = sB + t * 8;  bf16* sb1 = sB + (t + 256) * 8;

  floatx4 acc[4][4];
  #pragma unroll
  for (int j = 0; j < 4; ++j) {
    int c = n0 + wn + j * 16 + l16;
    float bv = __bfloat162float(fcb[c > VOCAB - 1 ? VOCAB - 1 : c]);
    #pragma unroll
    for (int i = 0; i < 4; ++i) acc[i][j] = (floatx4){bv, bv, bv, bv};
  }

  for (int kt = 0; kt < 32; ++kt) {
    gl_lds16(ga0, sa0); gl_lds16(ga1, sa1);
    gl_lds16(gb0, sb0); gl_lds16(gb1, sb1);
    ga0 += 32; ga1 += 32; gb0 += 32; gb1 += 32;
    __syncthreads();
    short8 af[4], bfr[4];
    #pragma unroll
    for (int i = 0; i < 4; ++i)
      af[i] = *(const short8*)(sA + (wm + i * 16 + l16) * 32 + quad * 8);
    #pragma unroll
    for (int j = 0; j < 4; ++j)
      bfr[j] = *(const short8*)(sB + (wn + j * 16 + l16) * 32 + quad * 8);
    #pragma unroll
    for (int i = 0; i < 4; ++i)
      #pragma unroll
      for (int j = 0; j < 4; ++j)
        acc[i][j] = MFMA(af[i], bfr[j], acc[i][j]);
    __syncthreads();
  }

  #pragma unroll
  for (int i = 0; i < 4; ++i)
    #pragma unroll
    for (int j = 0; j < 4; ++j)
      #pragma unroll
      for (int r = 0; r < 4; ++r) {
        int row = wm + i * 16 + quad * 4 + r;
        int col = n0 + wn + j * 16 + l16;
        if (col < VOCAB) {
          size_t o = (size_t)(m0 + row) * VOCAB + col;
          if (f) ((float*)outv)[o] = acc[i][j][r];
          else   ((bf16*)outv)[o] = __float2bfloat16(acc[i][j][r]);
        }
      }
}

// ---------------------------------------------------------------------------
extern "C" void kernel_launch(void* const* d_in, const int* in_sizes, int n_in,
                              void* d_out, int out_size, void* d_ws, size_t ws_size,
                              hipStream_t stream)
{
  const int*  tok     = (const int*)d_in[0];   // [128][64]
  const void* hid_raw = d_in[1];               // [2][64][1024]
  const void* emb_raw = d_in[2];               // [10000][1024]
  const void* Wx_raw  = d_in[3];               // [2][1024][1024]
  const void* Wh_raw  = d_in[4];               // [2][1024][1024]
  const void* b_raw   = d_in[5];               // [2][1024]
  const void* fcW_raw = d_in[6];               // [10000][1024]
  const void* fcb_raw = d_in[7];               // [10000]

  char* ws = (char*)d_ws;
  float* A0   = (float*)ws;                        //           0 .. 33,554,432  fp32 8192x1024
  bf16*  Wt   = (bf16*)(ws + 33554432);            //  33,554,432 .. 41,943,040  bf16 4x1024x1024
  bf16*  H1   = (bf16*)(ws + 41943040);            //  41,943,040 .. 58,720,256  bf16 8192x1024
  bf16*  h0a  = (bf16*)(ws + 58720256);            //  4 x 64x1024 ping-pong
  bf16*  h0b  = h0a + 65536;
  bf16*  h1a  = h0b + 65536;
  bf16*  h1b  = h1a + 65536;
  bf16*  embB = (bf16*)(ws + 59244544);            //  20,480,000 B
  bf16*  fcwB = (bf16*)(ws + 79724544);            //  20,480,000 B
  bf16*  bvecB= (bf16*)(ws + 100204544);           //  4,096 B
  bf16*  fcbB = (bf16*)(ws + 100208640);           //  20,000 B
  bf16*  hidB = (bf16*)(ws + 100228640);           //  262,144 B
  int*   flag = (int*)(ws + 100490784);            //  flag[0]=dtype, flag[1]=barrier

  detect<<<1, 256, 0, stream>>>((const unsigned short*)emb_raw, flag);
  convert_any<<<2048, 256, 0, stream>>>(emb_raw, embB, VOCAB * HID, flag);
  convert_any<<<2048, 256, 0, stream>>>(fcW_raw, fcwB, VOCAB * HID, flag);
  convert_any<<<8,    256, 0, stream>>>(b_raw,   bvecB, 2 * HID, flag);
  convert_any<<<40,   256, 0, stream>>>(fcb_raw, fcbB, VOCAB, flag);
  convert_any<<<512,  256, 0, stream>>>(hid_raw, hidB, 2 * BATCH * HID, flag);
  transpose4<<<dim3(16, 16, 4), 256, 0, stream>>>(Wx_raw, Wh_raw, Wt, flag);
  gemm_a0<<<dim3(64, 8), 256, 0, stream>>>(tok, embB, Wt, bvecB, A0);
  wavefront_persist<<<96, 256, 0, stream>>>(A0, Wt, bvecB, hidB,
                                            h0a, h0b, h1a, h1b, H1, d_out, flag);
  gemm_logits<<<dim3(64, 79), 256, 0, stream>>>(H1, fcwB, fcbB, d_out, flag);
}